// Round 10
// baseline (523.169 us; speedup 1.0000x reference)
//
#include <hip/hip_runtime.h>
#include <hip/hip_bf16.h>
#include <math.h>

#define NEG_SLOPE 0.2f
#define BIN_CHUNK 8192  // edges per k_bin block (32 KB private output window)
#define SCAP2 10240     // k_sort LDS staging capacity (coarse bucket ~8192+-90)

__device__ __forceinline__ unsigned f2bf(float f) {
  unsigned u = __float_as_uint(f);
  return (u + 0x7fffu + ((u >> 16) & 1u)) >> 16;  // RNE
}

// ---------------------------------------------------------------------------
// K1: h = x @ W + b_W (registers), emit:
//   hb [N][64] uint : {bf16 h(head0,d) lo | bf16 h(head1,d) hi}
//   ai [N][2], aj [N][2] : per-node attention scalars
// ---------------------------------------------------------------------------
__global__ __launch_bounds__(128) void k1_gemm(
    const float* __restrict__ x, const float* __restrict__ W,
    const float* __restrict__ bW, const float* __restrict__ att,
    unsigned int* __restrict__ hb, float* __restrict__ ai,
    float* __restrict__ aj, int Nn) {
  __shared__ float Ws[64 * 128];
  __shared__ float xs[64];
  __shared__ float bs[128];
  __shared__ float atts[256];
  __shared__ float hsh[128];
  int t = threadIdx.x;
  for (int i = t; i < 64 * 128; i += 128) Ws[i] = W[i];
  bs[t] = bW[t];
  atts[t] = att[t];
  atts[128 + t] = att[128 + t];
  __syncthreads();
  int head = t >> 6;
  int lane = t & 63;
  for (int row = blockIdx.x; row < Nn; row += gridDim.x) {
    if (t < 64) xs[t] = x[(size_t)row * 64 + t];
    __syncthreads();
    float acc = bs[t];
#pragma unroll
    for (int k = 0; k < 64; ++k) acc += xs[k] * Ws[k * 128 + t];
    hsh[t] = acc;
    float ti = atts[head * 128 + lane] * acc;
    float tj = atts[head * 128 + 64 + lane] * acc;
#pragma unroll
    for (int off = 32; off > 0; off >>= 1) {
      ti += __shfl_down(ti, off, 64);
      tj += __shfl_down(tj, off, 64);
    }
    if (lane == 0) { ai[row * 2 + head] = ti; aj[row * 2 + head] = tj; }
    __syncthreads();
    if (t < 64)
      hb[(size_t)row * 64 + t] = f2bf(hsh[t]) | (f2bf(hsh[64 + t]) << 16);
  }
}

// ---------------------------------------------------------------------------
// K_bin: local multi-split. Each block sorts its 8192-edge chunk by coarse
// bucket cb = dst>>8 and writes records into its PRIVATE contiguous window
// rec[start..start+chunk) (single-writer, L2-resident -> merged writebacks).
// Emits cnt_tbl/base_tbl[block][cb]. Also softmax denominators (f32 atomics).
// Record: {src:16 | (a0+5a1+25a2)<<16 | (dst&255)<<23}.
// ---------------------------------------------------------------------------
__global__ __launch_bounds__(256) void k_bin(
    const int* __restrict__ ei, const int* __restrict__ eattr,
    const float* __restrict__ att, const float* __restrict__ bemb,
    const float* __restrict__ ai, const float* __restrict__ aj,
    float* __restrict__ sden, unsigned int* __restrict__ rec,
    int* __restrict__ cnt_tbl, int* __restrict__ base_tbl, int Ee, int NCB) {
  __shared__ int hist[256];
  __shared__ int cur[256];
  __shared__ float tbl[30];
  int t = threadIdx.x;
  if (t < 30) {
    int f = t / 10, rem = t % 10, c = rem >> 1, hh = rem & 1;
    float sacc = 0.f;
    for (int d = 0; d < 64; ++d)
      sacc += att[hh * 128 + 64 + d] * bemb[(f * 5 + c) * 128 + hh * 64 + d];
    tbl[t] = sacc;
  }
  hist[t] = 0;
  __syncthreads();
  int start = blockIdx.x * BIN_CHUNK;
  int end = min(start + BIN_CHUNK, Ee);
  for (int e = start + t; e < end; e += 256)
    atomicAdd(&hist[ei[Ee + e] >> 8], 1);
  __syncthreads();
  if (t == 0) {
    int s = 0;
    for (int i = 0; i < NCB; ++i) { cur[i] = s; s += hist[i]; }
  }
  __syncthreads();
  if (t < NCB) {
    cnt_tbl[blockIdx.x * NCB + t] = hist[t];
    base_tbl[blockIdx.x * NCB + t] = cur[t];
  }
  __syncthreads();
  for (int e = start + t; e < end; e += 256) {
    int dst = ei[Ee + e];
    int src = ei[e];
    int a0 = eattr[e * 3], a1 = eattr[e * 3 + 1], a2 = eattr[e * 3 + 2];
    float lg0 = ai[dst * 2] + aj[src * 2] + tbl[a0 * 2] + tbl[10 + a1 * 2] +
                tbl[20 + a2 * 2];
    float lg1 = ai[dst * 2 + 1] + aj[src * 2 + 1] + tbl[a0 * 2 + 1] +
                tbl[10 + a1 * 2 + 1] + tbl[20 + a2 * 2 + 1];
    lg0 = lg0 >= 0.f ? lg0 : NEG_SLOPE * lg0;
    lg1 = lg1 >= 0.f ? lg1 : NEG_SLOPE * lg1;
    atomicAdd(&sden[src * 2], __expf(lg0));
    atomicAdd(&sden[src * 2 + 1], __expf(lg1));
    int cb = dst >> 8, dl = dst & 255;
    int pos = start + atomicAdd(&cur[cb], 1);
    rec[pos] = (unsigned)src | ((unsigned)(a0 + 5 * a1 + 25 * a2) << 16) |
               ((unsigned)dl << 23);
  }
}

// ---------------------------------------------------------------------------
// K_segoff: per-(cb,block) staging destinations + coarse-bucket bases.
// Single block; thread t owns coarse bucket t.
// ---------------------------------------------------------------------------
__global__ __launch_bounds__(256) void k_segoff(
    const int* __restrict__ cnt_tbl, int* __restrict__ segdst,
    int* __restrict__ coarse_base, int NCB, int NBLK, int Ee) {
  __shared__ int s[256];
  int t = threadIdx.x;
  int run = 0;
  if (t < NCB) {
    for (int blk = 0; blk < NBLK; ++blk) {
      segdst[t * NBLK + blk] = run;
      run += cnt_tbl[blk * NCB + t];
    }
  }
  s[t] = run;
  __syncthreads();
#pragma unroll
  for (int o = 1; o < 256; o <<= 1) {
    int xv = (t >= o) ? s[t - o] : 0;
    __syncthreads();
    s[t] += xv;
    __syncthreads();
  }
  if (t < NCB) coarse_base[t] = s[t] - run;  // exclusive
  if (t == 0) coarse_base[NCB] = Ee;
}

// ---------------------------------------------------------------------------
// K_sort: one block per coarse bucket (256 nodes). Gathers its segments into
// LDS, counting-sorts by node, recomputes ea (ai staged, aj/sden L2 reads),
// writes finished alpha + gather-format records into its PRIVATE contiguous
// window (merged writebacks) + per-node CSR offsets.
// ---------------------------------------------------------------------------
__global__ __launch_bounds__(256) void k_sort(
    const unsigned int* __restrict__ rec, const int* __restrict__ cnt_tbl,
    const int* __restrict__ base_tbl, const int* __restrict__ segdst,
    const int* __restrict__ coarse_base, const float2* __restrict__ ai2,
    const float2* __restrict__ aj2, const float2* __restrict__ sd2,
    const float* __restrict__ att, const float* __restrict__ bemb,
    unsigned int* __restrict__ eix2, float2* __restrict__ alpha2,
    int* __restrict__ off, int Nn, int NCB, int NBLK, int Ee) {
  __shared__ unsigned ubuf[SCAP2];
  __shared__ int hist[256], basex[256], curx[256];
  __shared__ float tbl[30];
  __shared__ float2 ais[256];
  int t = threadIdx.x;
  int cb = blockIdx.x;
  if (t < 30) {
    int f = t / 10, rem = t % 10, c = rem >> 1, hh = rem & 1;
    float sacc = 0.f;
    for (int d = 0; d < 64; ++d)
      sacc += att[hh * 128 + 64 + d] * bemb[(f * 5 + c) * 128 + hh * 64 + d];
    tbl[t] = sacc;
  }
  int node0 = cb << 8;
  if (node0 + t < Nn) ais[t] = ai2[node0 + t];
  hist[t] = 0;
  int gbase = coarse_base[cb];
  int total = coarse_base[cb + 1] - gbase;
  __syncthreads();
  int wave = t >> 6, lane = t & 63;
  bool fits = (total <= SCAP2);
  if (fits) {
    for (int blk = wave; blk < NBLK; blk += 4) {
      int len = cnt_tbl[blk * NCB + cb];
      int sp = blk * BIN_CHUNK + base_tbl[blk * NCB + cb];
      int dp = segdst[cb * NBLK + blk];
      for (int i = lane; i < len; i += 64) ubuf[dp + i] = rec[sp + i];
    }
  }
  __syncthreads();
  if (fits) {
    for (int i = t; i < total; i += 256)
      atomicAdd(&hist[(ubuf[i] >> 23) & 255], 1);
  } else {
    for (int blk = wave; blk < NBLK; blk += 4) {
      int len = cnt_tbl[blk * NCB + cb];
      int sp = blk * BIN_CHUNK + base_tbl[blk * NCB + cb];
      for (int i = lane; i < len; i += 64)
        atomicAdd(&hist[(rec[sp + i] >> 23) & 255], 1);
    }
  }
  __syncthreads();
  if (t == 0) {
    int s = 0;
    for (int i = 0; i < 256; ++i) { basex[i] = s; s += hist[i]; }
  }
  __syncthreads();
  curx[t] = basex[t];
  if (node0 + t < Nn) off[node0 + t] = gbase + basex[t];
  if (cb == 0 && t == 0) off[Nn] = Ee;
  __syncthreads();

#define PROC(UU)                                                               \
  {                                                                            \
    unsigned u = (UU);                                                         \
    int src = u & 0xFFFF;                                                      \
    int c012 = (u >> 16) & 127;                                                \
    int dl = (u >> 23) & 255;                                                  \
    int a0 = c012 % 5, a1 = (c012 / 5) % 5, a2 = c012 / 25;                    \
    float2 aiv = ais[dl];                                                      \
    float2 ajv = aj2[src];                                                     \
    float2 sdv = sd2[src];                                                     \
    float lg0 = aiv.x + ajv.x + tbl[a0 * 2] + tbl[10 + a1 * 2] + tbl[20 + a2 * 2]; \
    float lg1 = aiv.y + ajv.y + tbl[a0 * 2 + 1] + tbl[10 + a1 * 2 + 1] +       \
                tbl[20 + a2 * 2 + 1];                                          \
    lg0 = lg0 >= 0.f ? lg0 : NEG_SLOPE * lg0;                                  \
    lg1 = lg1 >= 0.f ? lg1 : NEG_SLOPE * lg1;                                  \
    float al0 = __expf(lg0) / (sdv.x + 1e-16f);                                \
    float al1 = __expf(lg1) / (sdv.y + 1e-16f);                                \
    int pos = gbase + atomicAdd(&curx[dl], 1);                                 \
    eix2[pos] = (unsigned)src | ((unsigned)a0 << 16) | ((unsigned)a1 << 19) |  \
                ((unsigned)a2 << 22);                                          \
    alpha2[pos] = make_float2(al0, al1);                                       \
  }

  if (fits) {
    for (int i = t; i < total; i += 256) PROC(ubuf[i])
  } else {
    for (int blk = wave; blk < NBLK; blk += 4) {
      int len = cnt_tbl[blk * NCB + cb];
      int sp = blk * BIN_CHUNK + base_tbl[blk * NCB + cb];
      for (int i = lane; i < len; i += 64) PROC(rec[sp + i])
    }
  }
#undef PROC
}

// ---------------------------------------------------------------------------
// K_gather: one wave per dst node, lane = d. Per edge: sequential rec+alpha
// reads, one coalesced hb gather, 2 FMA + predicated w-update. Edge-emb term
// hoisted: lanes 0..29 accumulate w[f,c,h]; epilogue adds 15-term weighted
// bemb sum. (Round-9 kernel; bit fields shifted: src 16b at 0, attrs at 16.)
// ---------------------------------------------------------------------------
__global__ __launch_bounds__(256) void k_gather(
    const unsigned int* __restrict__ eix, const float2* __restrict__ alpha2,
    const int* __restrict__ off, const unsigned int* __restrict__ hb,
    const float* __restrict__ bemb, const float* __restrict__ bias,
    float* __restrict__ out, int Nn) {
  __shared__ float bembs[15 * 128];  // [f*5+c][128]
  __shared__ float wsm[4][32];
  int t = threadIdx.x;
  for (int i = t; i < 15 * 128; i += 256) bembs[i] = bemb[i];
  __syncthreads();
  int wave = t >> 6, lane = t & 63;
  int n = blockIdx.x * 4 + wave;
  if (n >= Nn) return;
  int p0 = off[n], p1 = off[n + 1];
  int myf = lane / 10;
  int myc = (lane % 10) >> 1;
  bool myh = (lane & 1) != 0;
  bool active = lane < 30;
  float w = 0.f;
  float acc0 = 0.f, acc1 = 0.f;

#define EDGE_BODY(U, HV, AL)                                                   \
  {                                                                            \
    acc0 += AL.x * __uint_as_float(HV << 16);                                  \
    acc1 += AL.y * __uint_as_float(HV & 0xffff0000u);                          \
    int a0 = (U >> 16) & 7, a1 = (U >> 19) & 7, a2 = (U >> 22) & 7;            \
    int sel = myf == 0 ? a0 : (myf == 1 ? a1 : a2);                            \
    w += (active && myc == sel) ? (myh ? AL.y : AL.x) : 0.f;                   \
  }

  int p = p0;
  for (; p + 8 <= p1; p += 8) {
    unsigned u[8], hv[8];
    float2 al[8];
#pragma unroll
    for (int k = 0; k < 8; ++k) u[k] = eix[p + k];
#pragma unroll
    for (int k = 0; k < 8; ++k) al[k] = alpha2[p + k];
#pragma unroll
    for (int k = 0; k < 8; ++k)
      hv[k] = hb[(size_t)(u[k] & 0xFFFF) * 64 + lane];
#pragma unroll
    for (int k = 0; k < 8; ++k) EDGE_BODY(u[k], hv[k], al[k])
  }
  for (; p < p1; ++p) {
    unsigned u0 = eix[p];
    float2 al0 = alpha2[p];
    unsigned hv0 = hb[(size_t)(u0 & 0xFFFF) * 64 + lane];
    EDGE_BODY(u0, hv0, al0)
  }
#undef EDGE_BODY

  if (active) wsm[wave][lane] = w;  // same-wave LDS ops are in-order
#pragma unroll
  for (int k = 0; k < 15; ++k) {
    acc0 += wsm[wave][k * 2] * bembs[k * 128 + lane];
    acc1 += wsm[wave][k * 2 + 1] * bembs[k * 128 + 64 + lane];
  }
  out[(size_t)n * 64 + lane] = 0.5f * (acc0 + acc1) + bias[lane];
}

extern "C" void kernel_launch(void* const* d_in, const int* in_sizes, int n_in,
                              void* d_out, int out_size, void* d_ws, size_t ws_size,
                              hipStream_t stream) {
  const float* x    = (const float*)d_in[0];
  const int*   ei   = (const int*)d_in[1];
  const int*   eatt = (const int*)d_in[2];
  const float* W    = (const float*)d_in[3];
  const float* bW   = (const float*)d_in[4];
  const float* att  = (const float*)d_in[5];
  const float* bias = (const float*)d_in[6];
  const float* bemb = (const float*)d_in[7];
  int Nn = in_sizes[0] / 64;
  int Ee = in_sizes[1] / 2;
  int NCB = (Nn + 255) / 256;                      // 196 coarse buckets
  int NBLK = (Ee + BIN_CHUNK - 1) / BIN_CHUNK;     // 196 bin blocks

  char* ws = (char*)d_ws;
  ws = (char*)(((uintptr_t)ws + 15) & ~(uintptr_t)15);
  float* aj = (float*)ws;                 ws += (size_t)Nn * 2 * 4;
  float* sden = (float*)ws;               ws += (size_t)Nn * 2 * 4;
  float* ai = (float*)ws;                 ws += (size_t)Nn * 2 * 4;
  unsigned int* hb = (unsigned int*)ws;   ws += (size_t)Nn * 64 * 4;
  unsigned int* rec = (unsigned int*)ws;  ws += (size_t)NBLK * BIN_CHUNK * 4;
  unsigned int* eix2 = (unsigned int*)ws; ws += (size_t)Ee * 4;
  float2* alpha2 = (float2*)ws;           ws += (size_t)Ee * 8;
  int* off = (int*)ws;                    ws += (size_t)(Nn + 1) * 4;
  int* cnt_tbl = (int*)ws;                ws += (size_t)NBLK * NCB * 4;
  int* base_tbl = (int*)ws;               ws += (size_t)NBLK * NCB * 4;
  int* segdst = (int*)ws;                 ws += (size_t)NCB * NBLK * 4;
  int* coarse_base = (int*)ws;            ws += (size_t)(NCB + 1) * 4;

  hipMemsetAsync(sden, 0, (size_t)Nn * 2 * 4, stream);

  k1_gemm<<<1024, 128, 0, stream>>>(x, W, bW, att, hb, ai, aj, Nn);
  k_bin<<<NBLK, 256, 0, stream>>>(ei, eatt, att, bemb, ai, aj, sden, rec,
                                  cnt_tbl, base_tbl, Ee, NCB);
  k_segoff<<<1, 256, 0, stream>>>(cnt_tbl, segdst, coarse_base, NCB, NBLK, Ee);
  k_sort<<<NCB, 256, 0, stream>>>(rec, cnt_tbl, base_tbl, segdst, coarse_base,
                                  (const float2*)ai, (const float2*)aj,
                                  (const float2*)sden, att, bemb, eix2, alpha2,
                                  off, Nn, NCB, NBLK, Ee);
  k_gather<<<(Nn + 3) / 4, 256, 0, stream>>>(eix2, alpha2, off, hb, bemb, bias,
                                             (float*)d_out, Nn);
}